// Round 4
// baseline (287.790 us; speedup 1.0000x reference)
//
#include <hip/hip_runtime.h>

// CoL: out[p] = sum_{q in 3x3} W[q-p] * L[bin(x_q), bin(x_p)] * x_q
// B=32 C=64 H=128 W=128, L 5x5, zero pad, bin(x)=clamp(floor(5x),0,4).
//
// R4: the kernel is LDS-divergent-gather-instruction bound (~14 cyc per
// wave64 ds_read_b32 gather; R1-R3 all ran 102-109 us with the identical
// 4.72M-gather total despite big VALU/occupancy changes). Fix: fuse the
// three dw-terms of each (pixel, dr) into ONE ds_read_b128 from a 4D
// table T[dr][b0][b1][b2][bp] = float4(W[dr][0]*L[b0][bp],
// W[dr][1]*L[b1][bp], W[dr][2]*L[b2][bp], 0) -- 3*625*16B = 30 KB LDS.
// Gathers: 9/px -> 3/px. b128 divergent gather costs ~overhead + data,
// not 4x b32 (m134: b128 12cyc vs b32 5.8 stride-1), so expected ~2x.

namespace {
constexpr int H  = 128;
constexpr int WD = 128;
constexpr int PLANES = 32 * 64;        // 2048
constexpr int PX  = 8;                 // pixels per thread
constexpr int TPR = WD / PX;           // 16 threads per row
constexpr int RPB = 32;                // rows per block
constexpr int THREADS = RPB * TPR;     // 512
constexpr int TILES = H / RPB;         // 4
constexpr int TBL = 625;               // 5^4 float4 entries per dr
}

__global__ __launch_bounds__(THREADS) void col_kernel(
    const float* __restrict__ x, const float* __restrict__ Wf,
    const float* __restrict__ Lf, float* __restrict__ out)
{
    __shared__ float4 T[3 * TBL];      // T[dr*625 + ((b0*5+b1)*5+b2)*5+bp]

    const int t = threadIdx.x;

    // Build the fused table: 1875 float4 entries, ~3.7 per thread.
    // Entry e: dr = e/625; (b0,b1,b2,bp) = digits base-5 of e%625.
    for (int e = t; e < 3 * TBL; e += THREADS) {
        const int dr  = e / TBL;
        const int rem = e - dr * TBL;
        const int b0  = rem / 125;
        const int b1  = (rem / 25) % 5;
        const int b2  = (rem / 5) % 5;
        const int bp  = rem % 5;
        float4 v;
        v.x = Wf[dr * 3 + 0] * Lf[b0 * 5 + bp];
        v.y = Wf[dr * 3 + 1] * Lf[b1 * 5 + bp];
        v.z = Wf[dr * 3 + 2] * Lf[b2 * 5 + bp];
        v.w = 0.0f;
        T[e] = v;
    }
    __syncthreads();

    const int plane = blockIdx.x >> 2;           // / TILES
    const int row   = ((blockIdx.x & 3) << 5) + (t >> 4);
    const int col0  = (t & 15) * PX;
    const float* xp = x + (size_t)plane * (H * WD);

    // 3 rows x 10 cols window covering the 3x3 nbhd of 8 pixels.
    float win[3][PX + 2];
    #pragma unroll
    for (int dr = 0; dr < 3; ++dr) {
        const int rr = row + dr - 1;
        float4 c0 = make_float4(0.f, 0.f, 0.f, 0.f);
        float4 c1 = make_float4(0.f, 0.f, 0.f, 0.f);
        float l = 0.f, r = 0.f;
        if (rr >= 0 && rr < H) {
            const float* rp = xp + rr * WD + col0;
            c0 = *(const float4*)rp;             // 16B aligned
            c1 = *(const float4*)(rp + 4);
            if (col0 > 0)       l = rp[-1];      // exec-masked load
            if (col0 < WD - PX) r = rp[PX];
        }
        win[dr][0] = l;
        win[dr][1] = c0.x; win[dr][2] = c0.y; win[dr][3] = c0.z; win[dr][4] = c0.w;
        win[dr][5] = c1.x; win[dr][6] = c1.y; win[dr][7] = c1.z; win[dr][8] = c1.w;
        win[dr][9] = r;
    }

    float acc[PX];
    #pragma unroll
    for (int i = 0; i < PX; ++i) acc[i] = 0.f;

    const char* tb = (const char*)T;
    int bp16[PX];                       // center-pixel bin * 16 (byte)

    // Process one dr row: quantize its 10 window values, build byte-scaled
    // index components (b*2000, b*400, b*80), then 8 b128 gathers + 24 fma.
    // Streamed per-row to keep the live set small (R2/R3: big live sets ->
    // 44-48 VGPR allocation + rematerialization).
    auto do_row = [&](int drIdx) {
        int A[PX + 2], Bc[PX + 2], Cc[PX + 2];
        #pragma unroll
        for (int j = 0; j < PX + 2; ++j) {
            const int b = (int)fminf(win[drIdx][j] * 5.0f, 4.0f); // exact
            A[j]  = b * 2000;           // b0 stride: 125 entries * 16 B
            Bc[j] = b * 400;            // b1 stride:  25 * 16
            Cc[j] = b * 80;             // b2 stride:   5 * 16
            if (drIdx == 1) bp16[j > 0 ? j - 1 : 0] =
                (j >= 1 && j <= PX) ? (b << 4) : bp16[0];
        }
        float4 tv[PX];
        #pragma unroll
        for (int i = 0; i < PX; ++i) {
            const int addr = A[i] + Bc[i + 1] + Cc[i + 2] + bp16[i]
                           + drIdx * (TBL * 16);   // dr base folds into imm
            tv[i] = *(const float4*)(tb + addr);
        }
        #pragma unroll
        for (int i = 0; i < PX; ++i) {
            acc[i] = fmaf(tv[i].x, win[drIdx][i],     acc[i]);
            acc[i] = fmaf(tv[i].y, win[drIdx][i + 1], acc[i]);
            acc[i] = fmaf(tv[i].z, win[drIdx][i + 2], acc[i]);
        }
    };

    do_row(1);                          // center first: produces bp16
    do_row(0);
    do_row(2);

    float* op = out + (size_t)plane * (H * WD) + row * WD + col0;
    *(float4*)op       = make_float4(acc[0], acc[1], acc[2], acc[3]);
    *(float4*)(op + 4) = make_float4(acc[4], acc[5], acc[6], acc[7]);
}

extern "C" void kernel_launch(void* const* d_in, const int* in_sizes, int n_in,
                              void* d_out, int out_size, void* d_ws, size_t ws_size,
                              hipStream_t stream) {
    const float* x  = (const float*)d_in[0];   // input_tensor (B,C,H,W) fp32
    const float* Wf = (const float*)d_in[1];   // W (1,3,3) fp32
    const float* Lf = (const float*)d_in[2];   // L (5,5) fp32
    float* out = (float*)d_out;

    col_kernel<<<dim3(PLANES * TILES), dim3(THREADS), 0, stream>>>(x, Wf, Lf, out);
}